// Round 2
// baseline (2633.758 us; speedup 1.0000x reference)
//
#include <hip/hip_runtime.h>

typedef unsigned int u32;
typedef unsigned short u16;

typedef short short8 __attribute__((ext_vector_type(8)));
typedef float f32x4 __attribute__((ext_vector_type(4)));

// ---------------- numeric helpers ----------------

__device__ __forceinline__ float fast_exp2(float x) {
#if __has_builtin(__builtin_amdgcn_exp2f)
  return __builtin_amdgcn_exp2f(x);
#else
  return exp2f(x);
#endif
}
__device__ __forceinline__ float fast_rcp(float x) {
#if __has_builtin(__builtin_amdgcn_rcpf)
  return __builtin_amdgcn_rcpf(x);
#else
  return 1.0f / x;
#endif
}
__device__ __forceinline__ float sigmf_(float x) {
  return fast_rcp(1.0f + fast_exp2(-1.44269504088896f * x));
}
__device__ __forceinline__ float tanhf_(float x) {
  float e = fast_exp2(2.88539008177793f * x);  // exp(2x)
  return 1.0f - 2.0f * fast_rcp(e + 1.0f);
}
__device__ __forceinline__ u16 f2bf(float x) {
  u32 u = __float_as_uint(x);
  u32 r = (u + 0x7fffu + ((u >> 16) & 1u)) >> 16;
  return (u16)r;
}

#if __has_builtin(__builtin_amdgcn_fdot2_f32_bf16)
typedef __bf16 bf16x2_t __attribute__((ext_vector_type(2)));
__device__ __forceinline__ float dot2bf(u32 w, u32 h, float acc) {
  return __builtin_amdgcn_fdot2_f32_bf16(__builtin_bit_cast(bf16x2_t, w),
                                         __builtin_bit_cast(bf16x2_t, h), acc, false);
}
#else
__device__ __forceinline__ float dot2bf(u32 w, u32 h, float acc) {
  float wl = __uint_as_float(w << 16);
  float wh = __uint_as_float(w & 0xffff0000u);
  float hl = __uint_as_float(h << 16);
  float hh = __uint_as_float(h & 0xffff0000u);
  return fmaf(wh, hh, fmaf(wl, hl, acc));
}
#endif

// ---------------- threefry2x32 (JAX-exact) ----------------

__device__ __forceinline__ void tf_round(u32& x0, u32& x1, int r) {
  x0 += x1;
  x1 = (x1 << r) | (x1 >> (32 - r));
  x1 ^= x0;
}
__device__ void threefry(u32 k0, u32 k1, u32 c0, u32 c1, u32& o0, u32& o1) {
  u32 k2 = k0 ^ k1 ^ 0x1BD11BDAu;
  u32 x0 = c0 + k0, x1 = c1 + k1;
  tf_round(x0, x1, 13); tf_round(x0, x1, 15); tf_round(x0, x1, 26); tf_round(x0, x1, 6);
  x0 += k1; x1 += k2 + 1u;
  tf_round(x0, x1, 17); tf_round(x0, x1, 29); tf_round(x0, x1, 16); tf_round(x0, x1, 24);
  x0 += k2; x1 += k0 + 2u;
  tf_round(x0, x1, 13); tf_round(x0, x1, 15); tf_round(x0, x1, 26); tf_round(x0, x1, 6);
  x0 += k0; x1 += k1 + 3u;
  tf_round(x0, x1, 17); tf_round(x0, x1, 29); tf_round(x0, x1, 16); tf_round(x0, x1, 24);
  x0 += k1; x1 += k2 + 4u;
  tf_round(x0, x1, 13); tf_round(x0, x1, 15); tf_round(x0, x1, 26); tf_round(x0, x1, 6);
  x0 += k2; x1 += k0 + 5u;
  o0 = x0; o1 = x1;
}

#define JAX_PARTITIONABLE 1

// masks layout: [layer(2)][type(3: out,h,c)][b*256+h (16384)]
__global__ void masks_kernel(float* __restrict__ masks) {
  int gid = blockIdx.x * 256 + threadIdx.x;
  if (gid >= 2 * 3 * 16384) return;
  int l = gid / 49152;
  int rem = gid - l * 49152;
  int typ = rem / 16384;
  int i = rem - typ * 16384;
  u32 bits;
#if JAX_PARTITIONABLE
  u32 lk0, lk1, mk0, mk1, y0, y1;
  threefry(0u, 42u, 0u, (u32)l, lk0, lk1);      // split(MASK_KEY,2)[l]
  threefry(lk0, lk1, 0u, (u32)typ, mk0, mk1);   // split(layer_key,3)[typ]
  threefry(mk0, mk1, 0u, (u32)i, y0, y1);       // random_bits, counter = linear idx
  bits = y0 ^ y1;
#else
  u32 a0, a1, b0, b1;
  threefry(0u, 42u, 0u, 2u, a0, a1);
  threefry(0u, 42u, 1u, 3u, b0, b1);
  u32 lk0 = (l == 0) ? a0 : a1;
  u32 lk1 = (l == 0) ? b0 : b1;
  u32 e00, e01, e10, e11, e20, e21;
  threefry(lk0, lk1, 0u, 3u, e00, e01);
  threefry(lk0, lk1, 1u, 4u, e10, e11);
  threefry(lk0, lk1, 2u, 5u, e20, e21);
  u32 mk0 = (typ == 0) ? e00 : (typ == 1) ? e20 : e11;
  u32 mk1 = (typ == 0) ? e10 : (typ == 1) ? e01 : e21;
  u32 p = (i < 8192) ? (u32)i : (u32)(i - 8192);
  u32 y0, y1;
  threefry(mk0, mk1, p, p + 8192u, y0, y1);
  bits = (i < 8192) ? y0 : y1;
#endif
  float u = __uint_as_float((bits >> 9) | 0x3f800000u) - 1.0f;
  masks[gid] = (u < 0.75f) ? (1.0f / 0.75f) : 0.0f;
}

// ---------------- prep kernels ----------------

__global__ void conv_bf16(const float* __restrict__ src, u16* __restrict__ dst, int n) {
  int gid = blockIdx.x * 256 + threadIdx.x;
  if (gid < n) dst[gid] = f2bf(src[gid]);
}

// W [1024][256] f32 -> Wp [128 pairs][1024 rows] packed bf16x2 (pair p = k 2p,2p+1)
// also Ws [1024 rows][16] = pairs 112..127 contiguous per row (streamed tail)
__global__ void pack_whh(const float* __restrict__ W, u32* __restrict__ Wp, u32* __restrict__ Ws) {
  int gid = blockIdx.x * 256 + threadIdx.x;  // 131072
  int p = gid >> 10;
  int row = gid & 1023;
  u32 lo = f2bf(W[row * 256 + 2 * p]);
  u32 hi = f2bf(W[row * 256 + 2 * p + 1]);
  u32 v = lo | (hi << 16);
  Wp[p * 1024 + row] = v;
  if (p >= 112) Ws[row * 16 + (p - 112)] = v;
}

__global__ void add_bias(const float* __restrict__ a, const float* __restrict__ b,
                         float* __restrict__ o, int n) {
  int gid = blockIdx.x * 256 + threadIdx.x;
  if (gid < n) o[gid] = a[gid] + b[gid];
}

__global__ void init_flags(int* __restrict__ f) {
  f[blockIdx.x * 256 + threadIdx.x] = 0;
}

// ---------------- input-projection GEMM (bf16 MFMA), layer 1 only ----------------
__global__ __launch_bounds__(256) void gemm_xg(const u16* __restrict__ A,
                                               const u16* __restrict__ Bw,
                                               float* __restrict__ xg) {
  __shared__ uint4 Als[2048];  // [kb 0..31][m 0..63]
  __shared__ uint4 Bls[2048];
  int tid = threadIdx.x;
  int m0 = blockIdx.x * 64;
  int n0 = blockIdx.y * 64;
  {
    int row = tid >> 2, kseg = tid & 3;
    const uint4* Ag = (const uint4*)(A + (size_t)(m0 + row) * 256);
    const uint4* Bg = (const uint4*)(Bw + (size_t)(n0 + row) * 256);
#pragma unroll
    for (int uu = 0; uu < 8; ++uu) {
      int kb = kseg * 8 + uu;
      Als[kb * 64 + row] = Ag[kb];
      Bls[kb * 64 + row] = Bg[kb];
    }
  }
  __syncthreads();
  int w = tid >> 6, l = tid & 63;
  int wm = (w >> 1) * 32, wn = (w & 1) * 32;
  int lm = l & 15, q = l >> 4;
  f32x4 acc00 = {0.f, 0.f, 0.f, 0.f}, acc01 = acc00, acc10 = acc00, acc11 = acc00;
#pragma unroll
  for (int ks = 0; ks < 8; ++ks) {
    int kb = ks * 4 + q;
    short8 a0 = __builtin_bit_cast(short8, Als[kb * 64 + wm + lm]);
    short8 a1 = __builtin_bit_cast(short8, Als[kb * 64 + wm + 16 + lm]);
    short8 b0 = __builtin_bit_cast(short8, Bls[kb * 64 + wn + lm]);
    short8 b1 = __builtin_bit_cast(short8, Bls[kb * 64 + wn + 16 + lm]);
    acc00 = __builtin_amdgcn_mfma_f32_16x16x32_bf16(a0, b0, acc00, 0, 0, 0);
    acc01 = __builtin_amdgcn_mfma_f32_16x16x32_bf16(a0, b1, acc01, 0, 0, 0);
    acc10 = __builtin_amdgcn_mfma_f32_16x16x32_bf16(a1, b0, acc10, 0, 0, 0);
    acc11 = __builtin_amdgcn_mfma_f32_16x16x32_bf16(a1, b1, acc11, 0, 0, 0);
  }
#pragma unroll
  for (int fm = 0; fm < 2; ++fm)
#pragma unroll
    for (int fn = 0; fn < 2; ++fn) {
      f32x4 acc = (fm == 0) ? ((fn == 0) ? acc00 : acc01) : ((fn == 0) ? acc10 : acc11);
#pragma unroll
      for (int r = 0; r < 4; ++r) {
        int m = m0 + wm + fm * 16 + q * 4 + r;
        int n = n0 + wn + fn * 16 + lm;
        int bb = m >> 9, tt = m & 511;
        xg[(size_t)tt * 65536 + (size_t)bb * 1024 + n] = acc[r];
      }
    }
}

// ---------------- fused 3-stage pipelined recurrence ----------------
// blocks 0..63: layer-1 rec (produces out1 bf16 + flag1)
// blocks 64..127: layer-2 input projection (consumes out1, produces xg slots + flag2)
// blocks 128..191: layer-2 rec (consumes xg slots, produces final output)
#define REG_P 98
#define LDS_P 14
#define FLAG_EVERY 4

__device__ __forceinline__ void waitflag(const int* f, int want) {
  if (__hip_atomic_load(f, __ATOMIC_RELAXED, __HIP_MEMORY_SCOPE_AGENT) >= want) return;
  int n = 0;
  do {
    __builtin_amdgcn_s_sleep(2);
    if (++n > (1 << 18)) break;  // safety valve: wrong-answer beats hang
  } while (__hip_atomic_load(f, __ATOMIC_RELAXED, __HIP_MEMORY_SCOPE_AGENT) < want);
}
__device__ __forceinline__ u32 gloadu(const u32* p) {
  return __hip_atomic_load(p, __ATOMIC_RELAXED, __HIP_MEMORY_SCOPE_AGENT);
}
__device__ __forceinline__ float gloadf(const float* p) {
  u32 v = __hip_atomic_load((const u32*)p, __ATOMIC_RELAXED, __HIP_MEMORY_SCOPE_AGENT);
  return __uint_as_float(v);
}

__device__ __forceinline__ void load_weights(const u32* __restrict__ Wp,
                                             u32* wreg, u32* Wl, int r0, int r1) {
#pragma unroll
  for (int p = 0; p < REG_P; ++p) wreg[p] = Wp[p * 1024 + r0];
#pragma unroll
  for (int p = 0; p < REG_P; ++p) wreg[REG_P + p] = Wp[p * 1024 + r1];
#pragma unroll
  for (int s = 0; s < LDS_P; ++s) {
    Wl[s * 1024 + r0] = Wp[(REG_P + s) * 1024 + r0];
    Wl[s * 1024 + r1] = Wp[(REG_P + s) * 1024 + r1];
  }
}

// 128-pair matvec for rows r0,r1 against the 256-value bf16 vector in hbf.
// Streamed tail (pairs 112..127) is prefetched at top and consumed at the halfway
// point (~470 cyc later) to hide L2 latency. 2 accumulator chains per row for ILP.
__device__ __forceinline__ void matvec128(const u32* __restrict__ wreg,
                                          const u32* __restrict__ Wl,
                                          const uint4* __restrict__ Wsr0,
                                          const uint4* __restrict__ Wsr1,
                                          const u16* __restrict__ hbf,
                                          int r0, int r1, float& acc0, float& acc1) {
  const uint4* h4 = (const uint4*)hbf;
  uint4 st0[4], st1[4];
#pragma unroll
  for (int s4 = 0; s4 < 4; ++s4) { st0[s4] = Wsr0[s4]; st1[s4] = Wsr1[s4]; }
  float a0 = acc0, b0 = 0.f, a1 = acc1, b1 = 0.f;
#pragma unroll
  for (int qq = 0; qq < 14; ++qq) {
    uint4 hp = h4[qq];
    u32 hh[4] = {hp.x, hp.y, hp.z, hp.w};
#pragma unroll
    for (int e = 0; e < 4; ++e) {
      const int p = qq * 4 + e;
      u32 w0 = wreg[p];
      u32 w1 = wreg[REG_P + p];
      if (e & 1) { b0 = dot2bf(w0, hh[e], b0); b1 = dot2bf(w1, hh[e], b1); }
      else       { a0 = dot2bf(w0, hh[e], a0); a1 = dot2bf(w1, hh[e], a1); }
    }
  }
  // streamed tail: pairs 112..127 (loads are ~470 cycles old now)
#pragma unroll
  for (int s4 = 0; s4 < 4; ++s4) {
    uint4 hp = h4[28 + s4];
    a0 = dot2bf(st0[s4].x, hp.x, a0); a1 = dot2bf(st1[s4].x, hp.x, a1);
    b0 = dot2bf(st0[s4].y, hp.y, b0); b1 = dot2bf(st1[s4].y, hp.y, b1);
    a0 = dot2bf(st0[s4].z, hp.z, a0); a1 = dot2bf(st1[s4].z, hp.z, a1);
    b0 = dot2bf(st0[s4].w, hp.w, b0); b1 = dot2bf(st1[s4].w, hp.w, b1);
  }
#pragma unroll
  for (int qq = 14; qq < 28; ++qq) {
    uint4 hp = h4[qq];
    u32 hh[4] = {hp.x, hp.y, hp.z, hp.w};
#pragma unroll
    for (int e = 0; e < 4; ++e) {
      const int p = qq * 4 + e;
      u32 w0, w1;
      if (p < REG_P) {
        w0 = wreg[p];
        w1 = wreg[REG_P + p];
      } else {
        w0 = Wl[(p - REG_P) * 1024 + r0];
        w1 = Wl[(p - REG_P) * 1024 + r1];
      }
      if (e & 1) { b0 = dot2bf(w0, hh[e], b0); b1 = dot2bf(w1, hh[e], b1); }
      else       { a0 = dot2bf(w0, hh[e], a0); a1 = dot2bf(w1, hh[e], a1); }
    }
  }
  acc0 = a0 + b0;
  acc1 = a1 + b1;
}

__device__ void rec1_body(u32* Wl, float* gates, u16* hbf,
                          const u32* __restrict__ Wp, const uint4* __restrict__ Ws,
                          const float* __restrict__ xg, const float* __restrict__ bias,
                          const float* __restrict__ masks, u16* __restrict__ outB,
                          int* flag_out, int b) {
  const int tid = threadIdx.x;
  const int r0 = tid, r1 = tid + 512;
  u32 wreg[2 * REG_P];
  load_weights(Wp, wreg, Wl, r0, r1);
  if (tid < 256) hbf[tid] = 0;
  const float bias0 = bias[r0], bias1 = bias[r1];
  float c = 0.f, m_out = 0.f, m_h = 0.f, m_c = 0.f;
  if (tid < 256) {
    m_out = masks[b * 256 + tid];
    m_h   = masks[16384 + b * 256 + tid];
    m_c   = masks[32768 + b * 256 + tid];
  }
  const uint4* Wsr0 = Ws + (size_t)r0 * 4;
  const uint4* Wsr1 = Ws + (size_t)r1 * 4;
  const float* xgb = xg + b * 1024;
  __syncthreads();
  for (int t = 0; t < 512; ++t) {
    float xgv0 = xgb[(size_t)t * 65536 + r0];
    float xgv1 = xgb[(size_t)t * 65536 + r1];
    float acc0 = bias0, acc1 = bias1;
    matvec128(wreg, Wl, Wsr0, Wsr1, hbf, r0, r1, acc0, acc1);
    gates[r0] = acc0 + xgv0;
    gates[r1] = acc1 + xgv1;
    __syncthreads();
    if (tid < 256) {
      float gi = gates[tid];
      float gf = gates[tid + 256];
      float gg = gates[tid + 512];
      float go = gates[tid + 768];
      float fi = sigmf_(gi), ff = sigmf_(gf), fo = sigmf_(go);
      float tg = tanhf_(gg);
      c = ff * c + fi * tg;
      float hn = fo * tanhf_(c);
      float ov = hn * m_out;
      outB[t * 256 + tid] = f2bf(ov);
      hbf[tid] = f2bf(hn * m_h);
      c *= m_c;
    }
    __syncthreads();
    // barrier drained each wave's vmcnt; release (emits L2 writeback) makes
    // out1[..t] visible device-wide. Amortized: every FLAG_EVERY steps.
    if (((t & (FLAG_EVERY - 1)) == (FLAG_EVERY - 1)) && tid == 0)
      __hip_atomic_store(flag_out, t + 1, __ATOMIC_RELEASE, __HIP_MEMORY_SCOPE_AGENT);
  }
}

__device__ void proj_body(u32* Wl, u16* hbf,
                          const u32* __restrict__ Wp, const uint4* __restrict__ Ws,
                          const u32* __restrict__ xin, const float* __restrict__ bias,
                          float* __restrict__ xgout, int* flag_in, int* flag_out, int b) {
  const int tid = threadIdx.x;
  const int r0 = tid, r1 = tid + 512;
  u32 wreg[2 * REG_P];
  load_weights(Wp, wreg, Wl, r0, r1);
  const float bias0 = bias[r0], bias1 = bias[r1];
  const uint4* Wsr0 = Ws + (size_t)r0 * 4;
  const uint4* Wsr1 = Ws + (size_t)r1 * 4;
  float* xgb = xgout + b * 1024;
  u32* xl = (u32*)hbf;
  bool pf = false;
  u32 xr = 0;
  __syncthreads();
  for (int t = 0; t < 512; ++t) {
    if (!pf) {
      waitflag(flag_in, t + 1);
      __asm__ volatile("" ::: "memory");
      if (tid < 128) xr = gloadu(xin + t * 128 + tid);
    }
    if (tid < 128) xl[tid] = xr;
    __syncthreads();
    float acc0 = bias0, acc1 = bias1;
    matvec128(wreg, Wl, Wsr0, Wsr1, hbf, r0, r1, acc0, acc1);
    xgb[(size_t)t * 65536 + r0] = acc0;
    xgb[(size_t)t * 65536 + r1] = acc1;
    // prefetch next step's input if already published (hides agent-load latency)
    if (t < 511) {
      int fv = __hip_atomic_load(flag_in, __ATOMIC_RELAXED, __HIP_MEMORY_SCOPE_AGENT);
      fv = __builtin_amdgcn_readfirstlane(fv);
      pf = fv >= t + 2;
      if (pf) {
        __asm__ volatile("" ::: "memory");
        if (tid < 128) xr = gloadu(xin + (t + 1) * 128 + tid);
      }
    } else {
      pf = false;
    }
    __syncthreads();
    if (((t & (FLAG_EVERY - 1)) == (FLAG_EVERY - 1)) && tid == 0)
      __hip_atomic_store(flag_out, t + 1, __ATOMIC_RELEASE, __HIP_MEMORY_SCOPE_AGENT);
  }
}

__device__ void rec2_body(u32* Wl, float* gates, u16* hbf,
                          const u32* __restrict__ Wp, const uint4* __restrict__ Ws,
                          const float* __restrict__ xg, const float* __restrict__ masks,
                          float* __restrict__ outF, int* flag_in, int b) {
  const int tid = threadIdx.x;
  const int r0 = tid, r1 = tid + 512;
  u32 wreg[2 * REG_P];
  load_weights(Wp, wreg, Wl, r0, r1);
  if (tid < 256) hbf[tid] = 0;
  float c = 0.f, m_out = 0.f, m_h = 0.f, m_c = 0.f;
  if (tid < 256) {
    m_out = masks[b * 256 + tid];
    m_h   = masks[16384 + b * 256 + tid];
    m_c   = masks[32768 + b * 256 + tid];
  }
  const uint4* Wsr0 = Ws + (size_t)r0 * 4;
  const uint4* Wsr1 = Ws + (size_t)r1 * 4;
  const float* xgb = xg + b * 1024;
  bool pf = false;
  float pxg0 = 0.f, pxg1 = 0.f;
  __syncthreads();
  for (int t = 0; t < 512; ++t) {
    if (!pf) {
      waitflag(flag_in, t + 1);
      __asm__ volatile("" ::: "memory");
      pxg0 = gloadf(xgb + (size_t)t * 65536 + r0);
      pxg1 = gloadf(xgb + (size_t)t * 65536 + r1);
    }
    float acc0 = 0.f, acc1 = 0.f;  // bias already folded into proj output
    matvec128(wreg, Wl, Wsr0, Wsr1, hbf, r0, r1, acc0, acc1);
    gates[r0] = acc0 + pxg0;
    gates[r1] = acc1 + pxg1;
    // prefetch next step's xg if already published
    if (t < 511) {
      int fv = __hip_atomic_load(flag_in, __ATOMIC_RELAXED, __HIP_MEMORY_SCOPE_AGENT);
      fv = __builtin_amdgcn_readfirstlane(fv);
      pf = fv >= t + 2;
      if (pf) {
        __asm__ volatile("" ::: "memory");
        pxg0 = gloadf(xgb + (size_t)(t + 1) * 65536 + r0);
        pxg1 = gloadf(xgb + (size_t)(t + 1) * 65536 + r1);
      }
    } else {
      pf = false;
    }
    __syncthreads();
    if (tid < 256) {
      float gi = gates[tid];
      float gf = gates[tid + 256];
      float gg = gates[tid + 512];
      float go = gates[tid + 768];
      float fi = sigmf_(gi), ff = sigmf_(gf), fo = sigmf_(go);
      float tg = tanhf_(gg);
      c = ff * c + fi * tg;
      float hn = fo * tanhf_(c);
      float ov = hn * m_out;
      outF[t * 256 + tid] = ov;
      hbf[tid] = f2bf(hn * m_h);
      c *= m_c;
    }
    __syncthreads();
  }
}

__global__ __launch_bounds__(512) void lstm_fused(
    const u32* __restrict__ Wp0, const uint4* __restrict__ Ws0,
    const u32* __restrict__ WpI, const uint4* __restrict__ WsI,
    const u32* __restrict__ Wp1, const uint4* __restrict__ Ws1,
    float* __restrict__ xg, const float* __restrict__ biasb,
    const float* __restrict__ masks, u16* __restrict__ out1,
    float* __restrict__ outF, int* __restrict__ flags) {
  __shared__ u32 Wl[LDS_P * 1024];
  __shared__ alignas(16) float gates[1024];
  __shared__ alignas(16) u16 hbf[256];
  const int role = blockIdx.x >> 6;
  const int b = blockIdx.x & 63;
  int* flag1 = flags + b * 16;
  int* flag2 = flags + 1024 + b * 16;
  if (role == 0) {
    rec1_body(Wl, gates, hbf, Wp0, Ws0, xg, biasb, masks,
              out1 + (size_t)b * 131072, flag1, b);
  } else if (role == 1) {
    proj_body(Wl, hbf, WpI, WsI, (const u32*)(out1 + (size_t)b * 131072),
              biasb + 1024, xg, flag1, flag2, b);
  } else {
    rec2_body(Wl, gates, hbf, Wp1, Ws1, xg, masks + 49152,
              outF + (size_t)b * 131072, flag2, b);
  }
}

// ---------------- launch ----------------

extern "C" void kernel_launch(void* const* d_in, const int* in_sizes, int n_in,
                              void* d_out, int out_size, void* d_ws, size_t ws_size,
                              hipStream_t stream) {
  const float* x    = (const float*)d_in[0];
  const float* Wih0 = (const float*)d_in[1];
  const float* Whh0 = (const float*)d_in[2];
  const float* bih0 = (const float*)d_in[3];
  const float* bhh0 = (const float*)d_in[4];
  const float* Wih1 = (const float*)d_in[5];
  const float* Whh1 = (const float*)d_in[6];
  const float* bih1 = (const float*)d_in[7];
  const float* bhh1 = (const float*)d_in[8];
  float* out = (float*)d_out;

  char* w = (char*)d_ws;
  float* masks = (float*)(w + 0);             // 393216 B
  float* biasb = (float*)(w + 393216);        // 8192 B
  u32* Wp0     = (u32*)(w + 401408);          // 524288 B
  u32* Ws0     = (u32*)(w + 925696);          // 65536 B
  u32* Wp1     = (u32*)(w + 991232);          // 524288 B
  u32* Ws1     = (u32*)(w + 1515520);         // 65536 B
  u32* WpI     = (u32*)(w + 1581056);         // 524288 B
  u32* WsI     = (u32*)(w + 2105344);         // 65536 B
  u16* Wih0b   = (u16*)(w + 2170880);         // 524288 B
  u16* xb      = (u16*)(w + 2695168);         // 16777216 B
  u16* out1    = (u16*)(w + 19472384);        // 16777216 B
  int* flags   = (int*)(w + 36249600);        // 8192 B
  float* xg    = (float*)(w + 36257792);      // 134217728 B (total ~170.5 MB)

  hipLaunchKernelGGL(masks_kernel, dim3(384), dim3(256), 0, stream, masks);
  hipLaunchKernelGGL(conv_bf16, dim3(32768), dim3(256), 0, stream, x, xb, 8388608);
  hipLaunchKernelGGL(conv_bf16, dim3(1024), dim3(256), 0, stream, Wih0, Wih0b, 262144);
  hipLaunchKernelGGL(pack_whh, dim3(512), dim3(256), 0, stream, Whh0, Wp0, Ws0);
  hipLaunchKernelGGL(pack_whh, dim3(512), dim3(256), 0, stream, Whh1, Wp1, Ws1);
  hipLaunchKernelGGL(pack_whh, dim3(512), dim3(256), 0, stream, Wih1, WpI, WsI);
  hipLaunchKernelGGL(add_bias, dim3(4), dim3(256), 0, stream, bih0, bhh0, biasb, 1024);
  hipLaunchKernelGGL(add_bias, dim3(4), dim3(256), 0, stream, bih1, bhh1, biasb + 1024, 1024);
  hipLaunchKernelGGL(init_flags, dim3(8), dim3(256), 0, stream, flags);

  // layer-1 input projection (big MFMA GEMM), then the 3-stage pipelined recurrence
  hipLaunchKernelGGL(gemm_xg, dim3(512, 16), dim3(256), 0, stream, xb, Wih0b, xg);
  hipLaunchKernelGGL(lstm_fused, dim3(192), dim3(512), 0, stream,
                     Wp0, (const uint4*)Ws0, WpI, (const uint4*)WsI,
                     Wp1, (const uint4*)Ws1, xg, biasb, masks, out1, out, flags);
}